// Round 1
// 868.494 us; speedup vs baseline: 1.0045x; 1.0045x over previous
//
#include <hip/hip_runtime.h>
#include <hip/hip_bf16.h>

#define T_TOK 8192
#define DD 1024
#define EE 8
#define HH 4096
#define NA (2 * T_TOK)          // 16384 assignments
#define NBLK (NA / 256)         // 64 histogram/scatter blocks

typedef __bf16 bf16_t;
typedef __bf16 bf16x8 __attribute__((ext_vector_type(8)));
typedef __bf16 bf16x4 __attribute__((ext_vector_type(4)));
typedef float f32x4 __attribute__((ext_vector_type(4)));

#define GLDS(g, l) __builtin_amdgcn_global_load_lds( \
    (const __attribute__((address_space(1))) void*)(g), \
    (__attribute__((address_space(3))) void*)(l), 16, 0, 0)

// tanh-form GELU: gelu(v) = v * t / (t + 1), t = exp2(2/ln2 * u),
// u = 0.7978845608*(v + 0.044715 v^3). Max dev vs erf-GELU ~5e-4.
__device__ __forceinline__ float gelu_fast(float v) {
    float u = v * (0.79788456080286536f + 0.035677408136300125f * v * v);
    float a = 2.8853900817779268f * u;
    a = fminf(fmaxf(a, -87.0f), 87.0f);   // avoid inf/inf -> NaN
    float t = __builtin_amdgcn_exp2f(a);
    return v * t * __builtin_amdgcn_rcpf(t + 1.0f);
}

// ---------------- LayerNorm + gating (NO global atomics) ----------------
__global__ __launch_bounds__(256) void ln_gate_kernel(
    const float* __restrict__ x, const float* __restrict__ gamma,
    const float* __restrict__ beta, const float* __restrict__ gate_w,
    bf16_t* __restrict__ xn, int* __restrict__ tokexp, float* __restrict__ tokgate)
{
    const int t = blockIdx.x;
    const int tid = threadIdx.x;
    const int lane = tid & 63, wave = tid >> 6;
    __shared__ float wred[4];
    __shared__ float stats[2];
    __shared__ float lred[32];
    __shared__ float logitsS[8];

    float4 v = ((const float4*)(x + (size_t)t * DD))[tid];
    float s = v.x + v.y + v.z + v.w;
#pragma unroll
    for (int o = 32; o > 0; o >>= 1) s += __shfl_down(s, o, 64);
    if (lane == 0) wred[wave] = s;
    __syncthreads();
    if (tid == 0) stats[0] = (wred[0] + wred[1] + wred[2] + wred[3]) * (1.0f / DD);
    __syncthreads();
    const float mu = stats[0];
    float d0 = v.x - mu, d1 = v.y - mu, d2 = v.z - mu, d3 = v.w - mu;
    float q = d0*d0 + d1*d1 + d2*d2 + d3*d3;
#pragma unroll
    for (int o = 32; o > 0; o >>= 1) q += __shfl_down(q, o, 64);
    __syncthreads();
    if (lane == 0) wred[wave] = q;
    __syncthreads();
    if (tid == 0) stats[1] = rsqrtf((wred[0]+wred[1]+wred[2]+wred[3]) * (1.0f / DD) + 1e-5f);
    __syncthreads();
    const float rstd = stats[1];
    float4 g4 = ((const float4*)gamma)[tid];
    float4 b4 = ((const float4*)beta)[tid];
    float n0 = d0 * rstd * g4.x + b4.x;
    float n1 = d1 * rstd * g4.y + b4.y;
    float n2 = d2 * rstd * g4.z + b4.z;
    float n3 = d3 * rstd * g4.w + b4.w;
    bf16x4 pk = { (bf16_t)n0, (bf16_t)n1, (bf16_t)n2, (bf16_t)n3 };
    ((bf16x4*)(xn + (size_t)t * DD))[tid] = pk;

    float part[8];
#pragma unroll
    for (int e = 0; e < 8; ++e) {
        float4 gw = ((const float4*)(gate_w + (size_t)e * DD))[tid];
        part[e] = n0 * gw.x + n1 * gw.y + n2 * gw.z + n3 * gw.w;
    }
#pragma unroll
    for (int e = 0; e < 8; ++e) {
        float p = part[e];
#pragma unroll
        for (int o = 32; o > 0; o >>= 1) p += __shfl_down(p, o, 64);
        if (lane == 0) lred[wave * 8 + e] = p;
    }
    __syncthreads();
    if (tid < 8) logitsS[tid] = lred[tid] + lred[8 + tid] + lred[16 + tid] + lred[24 + tid];
    __syncthreads();
    if (tid == 0) {
        float best = -1e30f; int e0 = 0;
        for (int e = 0; e < 8; ++e) { float le = logitsS[e]; if (le > best) { best = le; e0 = e; } }
        float best2 = -1e30f; int e1 = (e0 == 0) ? 1 : 0;
        for (int e = 0; e < 8; ++e) if (e != e0) { float le = logitsS[e]; if (le > best2) { best2 = le; e1 = e; } }
        float z = expf(best2 - best);
        float g0 = 1.0f / (1.0f + z);
        float g1 = z * g0;
        tokexp[2*t] = e0; tokexp[2*t+1] = e1;
        tokgate[2*t] = g0; tokgate[2*t+1] = g1;
    }
}

// ---------------- per-block histogram (LDS atomics only) ----------------
__global__ __launch_bounds__(256) void hist_kernel(
    const int* __restrict__ tokexp, const float* __restrict__ tokgate,
    int* __restrict__ blockcnt, float* __restrict__ blockgsum)
{
    __shared__ int hcnt[EE];
    __shared__ float hg[EE];
    const int b = blockIdx.x, tid = threadIdx.x;
    if (tid < EE) { hcnt[tid] = 0; hg[tid] = 0.f; }
    __syncthreads();
    int idx = b * 256 + tid;
    int e = tokexp[idx];
    atomicAdd(&hcnt[e], 1);
    atomicAdd(&hg[e], tokgate[idx]);
    __syncthreads();
    if (tid < EE) {
        blockcnt[b * EE + tid] = hcnt[tid];
        blockgsum[b * EE + tid] = hg[tid];
    }
}

// ---------------- offsets + per-block bases + balance loss ----------------
__global__ __launch_bounds__(64) void offs_bal_kernel(
    const int* __restrict__ blockcnt, const float* __restrict__ blockgsum,
    int* __restrict__ cnt, int* __restrict__ offs, int* __restrict__ basep,
    float* __restrict__ bal_out)
{
    __shared__ int cntS[EE];
    const int tid = threadIdx.x;
    if (tid < EE) {
        int run = 0;
        for (int b = 0; b < NBLK; ++b) {
            basep[b * EE + tid] = run;
            run += blockcnt[b * EE + tid];
        }
        cnt[tid] = run;
        cntS[tid] = run;
    }
    __syncthreads();
    __shared__ int offsS[EE];
    if (tid == 0) {
        int run = 0; 
        for (int e = 0; e < EE; ++e) { offsS[e] = run; offs[e] = run; run += cntS[e]; }
        float bal = 0.f;
        for (int e = 0; e < EE; ++e) {
            float g = 0.f;
            for (int b = 0; b < NBLK; ++b) g += blockgsum[b * EE + e];
            float l = g * (1.0f / T_TOK) - (1.0f / EE);
            bal += l * l;
        }
        bal_out[0] = bal * (1.0f / EE);
    }
    __syncthreads();
    if (tid < EE) {
        for (int b = 0; b < NBLK; ++b) basep[b * EE + tid] += offsS[tid];
    }
}

// ---------------- scatter to assignment-major lists (LDS atomics only) ----------------
__global__ __launch_bounds__(256) void scatter_kernel(
    const int* __restrict__ tokexp, const float* __restrict__ tokgate,
    const int* __restrict__ basep,
    int* __restrict__ tok, float* __restrict__ gatev, int* __restrict__ a_of_t)
{
    __shared__ int hcnt[EE];
    const int b = blockIdx.x, tid = threadIdx.x;
    if (tid < EE) hcnt[tid] = 0;
    __syncthreads();
    int idx = b * 256 + tid;
    int e = tokexp[idx];
    int r = atomicAdd(&hcnt[e], 1);
    int a = basep[b * EE + e] + r;
    tok[a] = idx >> 1;
    gatev[a] = tokgate[idx];
    a_of_t[idx] = a;
}

// ---------------- fp32 [E][R][C] -> bf16 [E][C][R] transpose ----------------
__global__ __launch_bounds__(256) void convT_kernel(
    const float* __restrict__ in, bf16_t* __restrict__ out, int R, int C)
{
    __shared__ float tile[64][65];
    int e = blockIdx.z;
    int c0 = blockIdx.x * 64, r0 = blockIdx.y * 64;
    int tx = threadIdx.x & 63, ty = threadIdx.x >> 6;
    const float* src = in + ((size_t)e * R + r0) * C + c0;
#pragma unroll
    for (int i = 0; i < 16; ++i) {
        int r = ty + i * 4;
        tile[r][tx] = src[(size_t)r * C + tx];
    }
    __syncthreads();
    bf16_t* dst = out + ((size_t)e * C + c0) * R + r0;
#pragma unroll
    for (int i = 0; i < 16; ++i) {
        int cc = ty + i * 4;
        dst[(size_t)cc * R + tx] = (bf16_t)tile[tx][cc];
    }
}

// =====================================================================
// FFN GEMMs: 256x256 tile, BK=64, 8 waves (512 thr), double-buffered
// 128KB LDS, raw s_barrier + counted vmcnt(8), XOR bank swizzle
// (both-sides: inverse-swizzled glds source + swizzled ds_read addr),
// swapped MFMA operands so each lane owns 4 consecutive n -> bf16x4 store.
// =====================================================================

// ---------------- FFN1: h1 = gelu(xn[gathered] @ W1 + b1), bf16 out ----------------
__global__ __launch_bounds__(512, 2) void ffn1_kernel(
    const bf16_t* __restrict__ xn, const bf16_t* __restrict__ w1t,
    const float* __restrict__ b1, const int* __restrict__ tok,
    const int* __restrict__ cnt, const int* __restrict__ offs,
    bf16_t* __restrict__ h1)
{
    const int e = blockIdx.z;
    const int c = cnt[e];
    const int m0 = blockIdx.y * 256;
    if (m0 >= c) return;
    const int n0 = blockIdx.x * 256;
    const int off = offs[e];

    __shared__ __align__(16) bf16_t As[2][256 * 64];
    __shared__ __align__(16) bf16_t Bs[2][256 * 64];

    const int tid = threadIdx.x;
    const int rloc = tid >> 3;                     // 0..63: row within 64-row chunk
    const int qx8 = ((tid & 7) ^ (rloc & 7)) * 8;  // inverse-swizzled source col block

    int mA0 = m0 + rloc;        if (mA0 >= c) mA0 = c - 1;
    int mA1 = m0 + 64 + rloc;   if (mA1 >= c) mA1 = c - 1;
    int mA2 = m0 + 128 + rloc;  if (mA2 >= c) mA2 = c - 1;
    int mA3 = m0 + 192 + rloc;  if (mA3 >= c) mA3 = c - 1;
    const bf16_t* pa0 = xn + (size_t)tok[off + mA0] * DD + qx8;
    const bf16_t* pa1 = xn + (size_t)tok[off + mA1] * DD + qx8;
    const bf16_t* pa2 = xn + (size_t)tok[off + mA2] * DD + qx8;
    const bf16_t* pa3 = xn + (size_t)tok[off + mA3] * DD + qx8;
    const bf16_t* pb0 = w1t + ((size_t)e * HH + n0 + rloc) * DD + qx8;
    const bf16_t* pb1 = pb0 + (size_t)64 * DD;
    const bf16_t* pb2 = pb0 + (size_t)128 * DD;
    const bf16_t* pb3 = pb0 + (size_t)192 * DD;

    const int lane = tid & 63, wave = tid >> 6;
    const int wm = wave >> 2, wn = wave & 3;       // wave -> 128x64 output subtile
    const int l15 = lane & 15, lq = lane >> 4;
    const int rx = l15 & 7;
    const int rowA = (wm * 128 + l15) * 64;
    const int rowB = (wn * 64 + l15) * 64;
    const int cs0 = ((0 + lq) ^ rx) * 8;           // kk=0 swizzled col offset
    const int cs1 = ((4 + lq) ^ rx) * 8;           // kk=1

    f32x4 acc[8][4] = {};

    auto stage = [&](int buf) {
        bf16_t* la = &As[buf][tid * 8];
        bf16_t* lb = &Bs[buf][tid * 8];
        GLDS(pa0, la);          GLDS(pa1, la + 4096);
        GLDS(pa2, la + 8192);   GLDS(pa3, la + 12288);
        GLDS(pb0, lb);          GLDS(pb1, lb + 4096);
        GLDS(pb2, lb + 8192);   GLDS(pb3, lb + 12288);
        pa0 += 64; pa1 += 64; pa2 += 64; pa3 += 64;
        pb0 += 64; pb1 += 64; pb2 += 64; pb3 += 64;
    };

    stage(0);
    const int NT = DD / 64;   // 16
    for (int t = 0; t < NT; ++t) {
        const int cur = t & 1;
        if (t + 1 < NT) {
            stage(cur ^ 1);
            asm volatile("s_waitcnt vmcnt(8)" ::: "memory");  // cur tile done; next 8 in flight
        } else {
            asm volatile("s_waitcnt vmcnt(0)" ::: "memory");
        }
        __builtin_amdgcn_s_barrier();
        const bf16_t* Ab = &As[cur][0];
        const bf16_t* Bb = &Bs[cur][0];
#pragma unroll
        for (int kk = 0; kk < 2; ++kk) {
            const int cs = kk ? cs1 : cs0;
            bf16x8 wf[4], xf[8];
#pragma unroll
            for (int nf = 0; nf < 4; ++nf)
                wf[nf] = *(const bf16x8*)(Bb + rowB + nf * 1024 + cs);
#pragma unroll
            for (int tf = 0; tf < 8; ++tf)
                xf[tf] = *(const bf16x8*)(Ab + rowA + tf * 1024 + cs);
#pragma unroll
            for (int tf = 0; tf < 8; ++tf)
#pragma unroll
                for (int nf = 0; nf < 4; ++nf)
                    acc[tf][nf] = __builtin_amdgcn_mfma_f32_16x16x32_bf16(
                        wf[nf], xf[tf], acc[tf][nf], 0, 0, 0);
        }
        asm volatile("s_waitcnt lgkmcnt(0)" ::: "memory");  // reads complete before overwrite
        __builtin_amdgcn_s_barrier();
    }

    // epilogue: D frag has col=token (l15), row=n (lq*4+r) -> 4 consecutive n per lane
    const float* b1e = b1 + (size_t)e * HH;
#pragma unroll
    for (int tf = 0; tf < 8; ++tf) {
        int m = m0 + wm * 128 + tf * 16 + l15;
        if (m < c) {
            bf16_t* hrow = h1 + (size_t)(off + m) * HH;
#pragma unroll
            for (int nf = 0; nf < 4; ++nf) {
                int n = n0 + wn * 64 + nf * 16 + lq * 4;
                float4 bb = *(const float4*)(b1e + n);
                f32x4 a = acc[tf][nf];
                bf16x4 pk;
                pk[0] = (bf16_t)gelu_fast(a[0] + bb.x);
                pk[1] = (bf16_t)gelu_fast(a[1] + bb.y);
                pk[2] = (bf16_t)gelu_fast(a[2] + bb.z);
                pk[3] = (bf16_t)gelu_fast(a[3] + bb.w);
                *(bf16x4*)(hrow + n) = pk;
            }
        }
    }
}

// ---------------- FFN2: y = (h1 @ W2 + b2) * gate, bf16 out ----------------
__global__ __launch_bounds__(512, 2) void ffn2_kernel(
    const bf16_t* __restrict__ h1, const bf16_t* __restrict__ w2t,
    const float* __restrict__ b2, const float* __restrict__ gatev,
    const int* __restrict__ cnt, const int* __restrict__ offs,
    bf16_t* __restrict__ yv)
{
    const int e = blockIdx.z;
    const int c = cnt[e];
    const int m0 = blockIdx.y * 256;
    if (m0 >= c) return;
    const int n0 = blockIdx.x * 256;
    const int off = offs[e];

    __shared__ __align__(16) bf16_t As[2][256 * 64];
    __shared__ __align__(16) bf16_t Bs[2][256 * 64];

    const int tid = threadIdx.x;
    const int rloc = tid >> 3;
    const int qx8 = ((tid & 7) ^ (rloc & 7)) * 8;

    int mA0 = m0 + rloc;        if (mA0 >= c) mA0 = c - 1;
    int mA1 = m0 + 64 + rloc;   if (mA1 >= c) mA1 = c - 1;
    int mA2 = m0 + 128 + rloc;  if (mA2 >= c) mA2 = c - 1;
    int mA3 = m0 + 192 + rloc;  if (mA3 >= c) mA3 = c - 1;
    const bf16_t* pa0 = h1 + (size_t)(off + mA0) * HH + qx8;
    const bf16_t* pa1 = h1 + (size_t)(off + mA1) * HH + qx8;
    const bf16_t* pa2 = h1 + (size_t)(off + mA2) * HH + qx8;
    const bf16_t* pa3 = h1 + (size_t)(off + mA3) * HH + qx8;
    const bf16_t* pb0 = w2t + ((size_t)e * DD + n0 + rloc) * HH + qx8;
    const bf16_t* pb1 = pb0 + (size_t)64 * HH;
    const bf16_t* pb2 = pb0 + (size_t)128 * HH;
    const bf16_t* pb3 = pb0 + (size_t)192 * HH;

    const int lane = tid & 63, wave = tid >> 6;
    const int wm = wave >> 2, wn = wave & 3;
    const int l15 = lane & 15, lq = lane >> 4;
    const int rx = l15 & 7;
    const int rowA = (wm * 128 + l15) * 64;
    const int rowB = (wn * 64 + l15) * 64;
    const int cs0 = ((0 + lq) ^ rx) * 8;
    const int cs1 = ((4 + lq) ^ rx) * 8;

    f32x4 acc[8][4] = {};

    auto stage = [&](int buf) {
        bf16_t* la = &As[buf][tid * 8];
        bf16_t* lb = &Bs[buf][tid * 8];
        GLDS(pa0, la);          GLDS(pa1, la + 4096);
        GLDS(pa2, la + 8192);   GLDS(pa3, la + 12288);
        GLDS(pb0, lb);          GLDS(pb1, lb + 4096);
        GLDS(pb2, lb + 8192);   GLDS(pb3, lb + 12288);
        pa0 += 64; pa1 += 64; pa2 += 64; pa3 += 64;
        pb0 += 64; pb1 += 64; pb2 += 64; pb3 += 64;
    };

    stage(0);
    const int NT = HH / 64;   // 64
    for (int t = 0; t < NT; ++t) {
        const int cur = t & 1;
        if (t + 1 < NT) {
            stage(cur ^ 1);
            asm volatile("s_waitcnt vmcnt(8)" ::: "memory");
        } else {
            asm volatile("s_waitcnt vmcnt(0)" ::: "memory");
        }
        __builtin_amdgcn_s_barrier();
        const bf16_t* Ab = &As[cur][0];
        const bf16_t* Bb = &Bs[cur][0];
#pragma unroll
        for (int kk = 0; kk < 2; ++kk) {
            const int cs = kk ? cs1 : cs0;
            bf16x8 wf[4], xf[8];
#pragma unroll
            for (int nf = 0; nf < 4; ++nf)
                wf[nf] = *(const bf16x8*)(Bb + rowB + nf * 1024 + cs);
#pragma unroll
            for (int tf = 0; tf < 8; ++tf)
                xf[tf] = *(const bf16x8*)(Ab + rowA + tf * 1024 + cs);
#pragma unroll
            for (int tf = 0; tf < 8; ++tf)
#pragma unroll
                for (int nf = 0; nf < 4; ++nf)
                    acc[tf][nf] = __builtin_amdgcn_mfma_f32_16x16x32_bf16(
                        wf[nf], xf[tf], acc[tf][nf], 0, 0, 0);
        }
        asm volatile("s_waitcnt lgkmcnt(0)" ::: "memory");
        __builtin_amdgcn_s_barrier();
    }

    const float* b2e = b2 + (size_t)e * DD;
#pragma unroll
    for (int tf = 0; tf < 8; ++tf) {
        int m = m0 + wm * 128 + tf * 16 + l15;
        if (m < c) {
            float g = gatev[off + m];
            bf16_t* yrow = yv + (size_t)(off + m) * DD;
#pragma unroll
            for (int nf = 0; nf < 4; ++nf) {
                int n = n0 + wn * 64 + nf * 16 + lq * 4;
                float4 bb = *(const float4*)(b2e + n);
                f32x4 a = acc[tf][nf];
                bf16x4 pk;
                pk[0] = (bf16_t)((a[0] + bb.x) * g);
                pk[1] = (bf16_t)((a[1] + bb.y) * g);
                pk[2] = (bf16_t)((a[2] + bb.z) * g);
                pk[3] = (bf16_t)((a[3] + bb.w) * g);
                *(bf16x4*)(yrow + n) = pk;
            }
        }
    }
}

// ---------------- combine: out = x + y[a0] + y[a1] ----------------
__global__ __launch_bounds__(256) void combine_kernel(
    const float* __restrict__ x, const bf16_t* __restrict__ yv,
    const int* __restrict__ a_of_t, float* __restrict__ outp)
{
    int t = blockIdx.x;
    int tid = threadIdx.x;
    int a0 = a_of_t[2*t], a1 = a_of_t[2*t+1];
    float4 xv = ((const float4*)(x + (size_t)t * DD))[tid];
    bf16x4 y0 = ((const bf16x4*)(yv + (size_t)a0 * DD))[tid];
    bf16x4 y1 = ((const bf16x4*)(yv + (size_t)a1 * DD))[tid];
    float4 o;
    o.x = xv.x + (float)y0[0] + (float)y1[0];
    o.y = xv.y + (float)y0[1] + (float)y1[1];
    o.z = xv.z + (float)y0[2] + (float)y1[2];
    o.w = xv.w + (float)y0[3] + (float)y1[3];
    ((float4*)(outp + (size_t)t * DD))[tid] = o;
}

extern "C" void kernel_launch(void* const* d_in, const int* in_sizes, int n_in,
                              void* d_out, int out_size, void* d_ws, size_t ws_size,
                              hipStream_t stream)
{
    const float* x      = (const float*)d_in[0];
    const float* gamma  = (const float*)d_in[1];
    const float* beta   = (const float*)d_in[2];
    const float* gate_w = (const float*)d_in[3];
    const float* W1     = (const float*)d_in[4];
    const float* b1     = (const float*)d_in[5];
    const float* W2     = (const float*)d_in[6];
    const float* b2     = (const float*)d_in[7];
    float* outp = (float*)d_out;
    float* bal_out = outp + (size_t)T_TOK * DD;

    char* ws = (char*)d_ws;
    size_t off = 0;
    auto alloc = [&](size_t bytes) {
        char* p = ws + off;
        off += (bytes + 255) & ~(size_t)255;
        return p;
    };
    bf16_t* xn   = (bf16_t*)alloc((size_t)T_TOK * DD * 2);
    bf16_t* w1t  = (bf16_t*)alloc((size_t)EE * HH * DD * 2);
    bf16_t* w2t  = (bf16_t*)alloc((size_t)EE * DD * HH * 2);
    bf16_t* h1   = (bf16_t*)alloc((size_t)NA * HH * 2);
    bf16_t* yv   = (bf16_t*)alloc((size_t)NA * DD * 2);
    int*   tok     = (int*)alloc(NA * 4);
    float* gatev   = (float*)alloc(NA * 4);
    int*   a_of_t  = (int*)alloc(NA * 4);
    int*   tokexp  = (int*)alloc(NA * 4);
    float* tokgate = (float*)alloc(NA * 4);
    int*   blockcnt  = (int*)alloc(NBLK * EE * 4);
    float* blockgsum = (float*)alloc(NBLK * EE * 4);
    int*   basep     = (int*)alloc(NBLK * EE * 4);
    int*   cnt  = (int*)alloc(EE * 4);
    int*   offs = (int*)alloc(EE * 4);

    convT_kernel<<<dim3(HH/64, DD/64, EE), 256, 0, stream>>>(W1, w1t, DD, HH);
    convT_kernel<<<dim3(DD/64, HH/64, EE), 256, 0, stream>>>(W2, w2t, HH, DD);
    ln_gate_kernel<<<T_TOK, 256, 0, stream>>>(x, gamma, beta, gate_w, xn, tokexp, tokgate);
    hist_kernel<<<NBLK, 256, 0, stream>>>(tokexp, tokgate, blockcnt, blockgsum);
    offs_bal_kernel<<<1, 64, 0, stream>>>(blockcnt, blockgsum, cnt, offs, basep, bal_out);
    scatter_kernel<<<NBLK, 256, 0, stream>>>(tokexp, tokgate, basep, tok, gatev, a_of_t);
    ffn1_kernel<<<dim3(HH/256, 32, EE), 512, 0, stream>>>(xn, w1t, b1, tok, cnt, offs, h1);
    ffn2_kernel<<<dim3(DD/256, 32, EE), 512, 0, stream>>>(h1, w2t, b2, gatev, cnt, offs, yv);
    combine_kernel<<<T_TOK, 256, 0, stream>>>(x, yv, a_of_t, outp);
}

// Round 3
// 781.742 us; speedup vs baseline: 1.1160x; 1.1110x over previous
//
#include <hip/hip_runtime.h>
#include <hip/hip_bf16.h>

#define T_TOK 8192
#define DD 1024
#define EE 8
#define HH 4096
#define NA (2 * T_TOK)          // 16384 assignments
#define NBLK (NA / 256)         // 64 histogram/scatter blocks

typedef __bf16 bf16_t;
typedef __bf16 bf16x8 __attribute__((ext_vector_type(8)));
typedef __bf16 bf16x4 __attribute__((ext_vector_type(4)));
typedef float f32x4 __attribute__((ext_vector_type(4)));
typedef int   i32x4 __attribute__((ext_vector_type(4)));

union frag_u { i32x4 i; bf16x8 b; };

#define GLDS(g, l) __builtin_amdgcn_global_load_lds( \
    (const __attribute__((address_space(1))) void*)(g), \
    (__attribute__((address_space(3))) void*)(l), 16, 0, 0)

// inline-asm ds_read_b128: invisible to the memory legalizer (no auto vmcnt(0))
#define DSR(d, a)      asm volatile("ds_read_b128 %0, %1"           : "=v"(d) : "v"(a))
#define DSRO(d, a, O)  asm volatile("ds_read_b128 %0, %1 offset:" O : "=v"(d) : "v"(a))

#define VMW(N) asm volatile("s_waitcnt vmcnt(" #N ")" ::: "memory")

// tanh-form GELU: gelu(v) = v * t / (t + 1), t = exp2(2/ln2 * u),
// u = 0.7978845608*(v + 0.044715 v^3). Max dev vs erf-GELU ~5e-4.
__device__ __forceinline__ float gelu_fast(float v) {
    float u = v * (0.79788456080286536f + 0.035677408136300125f * v * v);
    float a = 2.8853900817779268f * u;
    a = fminf(fmaxf(a, -87.0f), 87.0f);
    float t = __builtin_amdgcn_exp2f(a);
    return v * t * __builtin_amdgcn_rcpf(t + 1.0f);
}

// ---------------- LayerNorm + gating ----------------
__global__ __launch_bounds__(256) void ln_gate_kernel(
    const float* __restrict__ x, const float* __restrict__ gamma,
    const float* __restrict__ beta, const float* __restrict__ gate_w,
    bf16_t* __restrict__ xn, int* __restrict__ tokexp, float* __restrict__ tokgate)
{
    const int t = blockIdx.x;
    const int tid = threadIdx.x;
    const int lane = tid & 63, wave = tid >> 6;
    __shared__ float wred[4];
    __shared__ float stats[2];
    __shared__ float lred[32];
    __shared__ float logitsS[8];

    float4 v = ((const float4*)(x + (size_t)t * DD))[tid];
    float s = v.x + v.y + v.z + v.w;
#pragma unroll
    for (int o = 32; o > 0; o >>= 1) s += __shfl_down(s, o, 64);
    if (lane == 0) wred[wave] = s;
    __syncthreads();
    if (tid == 0) stats[0] = (wred[0] + wred[1] + wred[2] + wred[3]) * (1.0f / DD);
    __syncthreads();
    const float mu = stats[0];
    float d0 = v.x - mu, d1 = v.y - mu, d2 = v.z - mu, d3 = v.w - mu;
    float q = d0*d0 + d1*d1 + d2*d2 + d3*d3;
#pragma unroll
    for (int o = 32; o > 0; o >>= 1) q += __shfl_down(q, o, 64);
    __syncthreads();
    if (lane == 0) wred[wave] = q;
    __syncthreads();
    if (tid == 0) stats[1] = rsqrtf((wred[0]+wred[1]+wred[2]+wred[3]) * (1.0f / DD) + 1e-5f);
    __syncthreads();
    const float rstd = stats[1];
    float4 g4 = ((const float4*)gamma)[tid];
    float4 b4 = ((const float4*)beta)[tid];
    float n0 = d0 * rstd * g4.x + b4.x;
    float n1 = d1 * rstd * g4.y + b4.y;
    float n2 = d2 * rstd * g4.z + b4.z;
    float n3 = d3 * rstd * g4.w + b4.w;
    bf16x4 pk = { (bf16_t)n0, (bf16_t)n1, (bf16_t)n2, (bf16_t)n3 };
    ((bf16x4*)(xn + (size_t)t * DD))[tid] = pk;

    float part[8];
#pragma unroll
    for (int e = 0; e < 8; ++e) {
        float4 gw = ((const float4*)(gate_w + (size_t)e * DD))[tid];
        part[e] = n0 * gw.x + n1 * gw.y + n2 * gw.z + n3 * gw.w;
    }
#pragma unroll
    for (int e = 0; e < 8; ++e) {
        float p = part[e];
#pragma unroll
        for (int o = 32; o > 0; o >>= 1) p += __shfl_down(p, o, 64);
        if (lane == 0) lred[wave * 8 + e] = p;
    }
    __syncthreads();
    if (tid < 8) logitsS[tid] = lred[tid] + lred[8 + tid] + lred[16 + tid] + lred[24 + tid];
    __syncthreads();
    if (tid == 0) {
        float best = -1e30f; int e0 = 0;
        for (int e = 0; e < 8; ++e) { float le = logitsS[e]; if (le > best) { best = le; e0 = e; } }
        float best2 = -1e30f; int e1 = (e0 == 0) ? 1 : 0;
        for (int e = 0; e < 8; ++e) if (e != e0) { float le = logitsS[e]; if (le > best2) { best2 = le; e1 = e; } }
        float z = expf(best2 - best);
        float g0 = 1.0f / (1.0f + z);
        float g1 = z * g0;
        tokexp[2*t] = e0; tokexp[2*t+1] = e1;
        tokgate[2*t] = g0; tokgate[2*t+1] = g1;
    }
}

// ---------------- per-block histogram ----------------
__global__ __launch_bounds__(256) void hist_kernel(
    const int* __restrict__ tokexp, const float* __restrict__ tokgate,
    int* __restrict__ blockcnt, float* __restrict__ blockgsum)
{
    __shared__ int hcnt[EE];
    __shared__ float hg[EE];
    const int b = blockIdx.x, tid = threadIdx.x;
    if (tid < EE) { hcnt[tid] = 0; hg[tid] = 0.f; }
    __syncthreads();
    int idx = b * 256 + tid;
    int e = tokexp[idx];
    atomicAdd(&hcnt[e], 1);
    atomicAdd(&hg[e], tokgate[idx]);
    __syncthreads();
    if (tid < EE) {
        blockcnt[b * EE + tid] = hcnt[tid];
        blockgsum[b * EE + tid] = hg[tid];
    }
}

// ---------------- offsets + per-block bases + balance loss ----------------
__global__ __launch_bounds__(64) void offs_bal_kernel(
    const int* __restrict__ blockcnt, const float* __restrict__ blockgsum,
    int* __restrict__ cnt, int* __restrict__ offs, int* __restrict__ basep,
    float* __restrict__ bal_out)
{
    __shared__ int cntS[EE];
    const int tid = threadIdx.x;
    if (tid < EE) {
        int run = 0;
        for (int b = 0; b < NBLK; ++b) {
            basep[b * EE + tid] = run;
            run += blockcnt[b * EE + tid];
        }
        cnt[tid] = run;
        cntS[tid] = run;
    }
    __syncthreads();
    __shared__ int offsS[EE];
    if (tid == 0) {
        int run = 0; 
        for (int e = 0; e < EE; ++e) { offsS[e] = run; offs[e] = run; run += cntS[e]; }
        float bal = 0.f;
        for (int e = 0; e < EE; ++e) {
            float g = 0.f;
            for (int b = 0; b < NBLK; ++b) g += blockgsum[b * EE + e];
            float l = g * (1.0f / T_TOK) - (1.0f / EE);
            bal += l * l;
        }
        bal_out[0] = bal * (1.0f / EE);
    }
    __syncthreads();
    if (tid < EE) {
        for (int b = 0; b < NBLK; ++b) basep[b * EE + tid] += offsS[tid];
    }
}

// ---------------- scatter to assignment-major lists ----------------
__global__ __launch_bounds__(256) void scatter_kernel(
    const int* __restrict__ tokexp, const float* __restrict__ tokgate,
    const int* __restrict__ basep,
    int* __restrict__ tok, float* __restrict__ gatev, int* __restrict__ a_of_t)
{
    __shared__ int hcnt[EE];
    const int b = blockIdx.x, tid = threadIdx.x;
    if (tid < EE) hcnt[tid] = 0;
    __syncthreads();
    int idx = b * 256 + tid;
    int e = tokexp[idx];
    int r = atomicAdd(&hcnt[e], 1);
    int a = basep[b * EE + e] + r;
    tok[a] = idx >> 1;
    gatev[a] = tokgate[idx];
    a_of_t[idx] = a;
}

// ---------------- fp32 [E][R][C] -> bf16 [E][C][R] transpose ----------------
__global__ __launch_bounds__(256) void convT_kernel(
    const float* __restrict__ in, bf16_t* __restrict__ out, int R, int C)
{
    __shared__ float tile[64][65];
    int e = blockIdx.z;
    int c0 = blockIdx.x * 64, r0 = blockIdx.y * 64;
    int tx = threadIdx.x & 63, ty = threadIdx.x >> 6;
    const float* src = in + ((size_t)e * R + r0) * C + c0;
#pragma unroll
    for (int i = 0; i < 16; ++i) {
        int r = ty + i * 4;
        tile[r][tx] = src[(size_t)r * C + tx];
    }
    __syncthreads();
    bf16_t* dst = out + ((size_t)e * C + c0) * R + r0;
#pragma unroll
    for (int i = 0; i < 16; ++i) {
        int cc = ty + i * 4;
        dst[(size_t)cc * R + tx] = (bf16_t)tile[tx][cc];
    }
}

// =====================================================================
// 256x256 tile, BK=64, 8 waves, 4-phase-per-K-tile schedule.
// LDS layout per buffer (bf16 elems): A rows 0-127 @0, B rows 0-127 @8192,
// A rows 128-255 @16384, B rows 128-255 @24576 (each 64-row unit = 4096).
// Wave (wm,wn): rows wm*128+{0..127}; cols per phase nq: nq*128+wn*32+{0..31}.
// Phase reads:  ph0 {A0,Blo}  ph1 {A1}  ph2 {Bhi}  ph3 {A0}
// Phase stages: ph0 A0'  ph1 Blo'  ph2 A1'  ph3 Bhi'   (vmcnt(4) each)
// => entering ph0 only {A1,Bhi} of current tile may be in flight; each is
//    landed by the vmcnt(4)+barrier preceding its consuming phase.
// =====================================================================

#define MM(tf, nf) \
    acc[tf][nf] = __builtin_amdgcn_mfma_f32_16x16x32_bf16(bB[(nf)&1][0].b, aA[(tf)&3][0].b, acc[tf][nf], 0,0,0); \
    acc[tf][nf] = __builtin_amdgcn_mfma_f32_16x16x32_bf16(bB[(nf)&1][1].b, aA[(tf)&3][1].b, acc[tf][nf], 0,0,0);

#define MFMA16(mq, nq) \
    MM((mq)*4+0, (nq)*2+0) MM((mq)*4+0, (nq)*2+1) \
    MM((mq)*4+1, (nq)*2+0) MM((mq)*4+1, (nq)*2+1) \
    MM((mq)*4+2, (nq)*2+0) MM((mq)*4+2, (nq)*2+1) \
    MM((mq)*4+3, (nq)*2+0) MM((mq)*4+3, (nq)*2+1)

#define LOAD_A(mq_) do { \
    uint32_t a0_ = abase0 + rb + (mq_)*8192u; \
    uint32_t a1_ = abase1 + rb + (mq_)*8192u; \
    DSR (aA[0][0].i, a0_); DSRO(aA[1][0].i, a0_, "2048"); \
    DSRO(aA[2][0].i, a0_, "4096"); DSRO(aA[3][0].i, a0_, "6144"); \
    DSR (aA[0][1].i, a1_); DSRO(aA[1][1].i, a1_, "2048"); \
    DSRO(aA[2][1].i, a1_, "4096"); DSRO(aA[3][1].i, a1_, "6144"); \
} while (0)

#define LOAD_B(nq_) do { \
    uint32_t b0_ = bbase0 + rb + (nq_)*32768u; \
    uint32_t b1_ = bbase1 + rb + (nq_)*32768u; \
    DSR (bB[0][0].i, b0_); DSRO(bB[1][0].i, b0_, "2048"); \
    DSR (bB[0][1].i, b1_); DSRO(bB[1][1].i, b1_, "2048"); \
} while (0)

#define PHASE_MID() do { \
    __builtin_amdgcn_s_barrier(); \
    asm volatile("s_waitcnt lgkmcnt(0)" ::: "memory"); \
    __builtin_amdgcn_sched_barrier(0); \
    __builtin_amdgcn_s_setprio(1); \
} while (0)

#define PHASE_END() do { \
    __builtin_amdgcn_s_setprio(0); \
    __builtin_amdgcn_s_barrier(); \
} while (0)

template<int NT>
__device__ __forceinline__ void mfma_mainloop(
    const bf16_t* pa0, const bf16_t* pa1, const bf16_t* pa2, const bf16_t* pa3,
    const bf16_t* pb0, const bf16_t* pb1, const bf16_t* pb2, const bf16_t* pb3,
    bf16_t* S, f32x4 (&acc)[8][4])
{
    const int tid = threadIdx.x;
    const int lane = tid & 63, wave = tid >> 6;
    const int wm = wave >> 2, wn = wave & 3;
    const int l15 = lane & 15, lq = lane >> 4, rx = l15 & 7;
    const uint32_t csb0 = (uint32_t)((lq ^ rx) * 16);
    const uint32_t csb1 = (uint32_t)(((4 + lq) ^ rx) * 16);
    const uint32_t sbase = (uint32_t)(size_t)(__attribute__((address_space(3))) bf16_t*)S;
    const uint32_t abase0 = sbase + (uint32_t)wm*32768u + (uint32_t)l15*128u + csb0;
    const uint32_t abase1 = sbase + (uint32_t)wm*32768u + (uint32_t)l15*128u + csb1;
    const uint32_t bbase0 = sbase + 16384u + (uint32_t)wn*4096u + (uint32_t)l15*128u + csb0;
    const uint32_t bbase1 = sbase + 16384u + (uint32_t)wn*4096u + (uint32_t)l15*128u + csb1;

    frag_u aA[4][2];
    frag_u bB[2][2];

    // prologue: stage tile 0; issue order = {A0-pair, Blo-pair, A1-pair, Bhi-pair}
    {
        bf16_t* wb = S;
        GLDS(pa0, wb +     0 + tid*8); pa0 += 64;   // A rows   0- 63
        GLDS(pa2, wb + 16384 + tid*8); pa2 += 64;   // A rows 128-191
        GLDS(pb0, wb +  8192 + tid*8); pb0 += 64;   // B rows   0- 63
        GLDS(pb1, wb + 12288 + tid*8); pb1 += 64;   // B rows  64-127
        GLDS(pa1, wb +  4096 + tid*8); pa1 += 64;   // A rows  64-127
        GLDS(pa3, wb + 20480 + tid*8); pa3 += 64;   // A rows 192-255
        GLDS(pb2, wb + 24576 + tid*8); pb2 += 64;   // B rows 128-191
        GLDS(pb3, wb + 28672 + tid*8); pb3 += 64;   // B rows 192-255
    }
    VMW(4);                    // lands A0-pair + Blo-pair (= ph0's read set)
    __builtin_amdgcn_s_barrier();

    for (int kt = 0; kt < NT; ++kt) {
        const uint32_t rb = (uint32_t)(kt & 1) * 65536u;
        bf16_t* wb = S + (size_t)(((kt + 1) & 1)) * 32768;
        const bool more = (kt + 1 < NT);

        // ---- phase 0: (mq=0, nq=0) reads A0+Blo; stage next A0-pair
        LOAD_A(0); LOAD_B(0);
        if (more) {
            GLDS(pa0, wb +     0 + tid*8); pa0 += 64;
            GLDS(pa2, wb + 16384 + tid*8); pa2 += 64;
            VMW(4);            // lands A1(kt)
        } else VMW(2);         // lands A1(kt)
        PHASE_MID();
        MFMA16(0, 0)
        PHASE_END();

        // ---- phase 1: (mq=1, nq=0) reads A1; stage next Blo-pair
        LOAD_A(1);
        if (more) {
            GLDS(pb0, wb +  8192 + tid*8); pb0 += 64;
            GLDS(pb1, wb + 12288 + tid*8); pb1 += 64;
            VMW(4);            // lands Bhi(kt)
        } else VMW(0);         // lands Bhi(kt)
        PHASE_MID();
        MFMA16(1, 0)
        PHASE_END();

        // ---- phase 2: (mq=1, nq=1) reads Bhi; stage next A1-pair
        LOAD_B(1);
        if (more) {
            GLDS(pa1, wb +  4096 + tid*8); pa1 += 64;
            GLDS(pa3, wb + 20480 + tid*8); pa3 += 64;
            VMW(4);            // lands A0(kt+1)
        }
        PHASE_MID();
        MFMA16(1, 1)
        PHASE_END();

        // ---- phase 3: (mq=0, nq=1) reads A0 (again); stage next Bhi-pair
        LOAD_A(0);
        if (more) {
            GLDS(pb2, wb + 24576 + tid*8); pb2 += 64;
            GLDS(pb3, wb + 28672 + tid*8); pb3 += 64;
            VMW(4);            // lands Blo(kt+1)
        }
        PHASE_MID();
        MFMA16(0, 1)
        PHASE_END();
    }
}

// ---------------- FFN1: h1 = gelu(xn[gathered] @ W1 + b1) ----------------
__global__ __launch_bounds__(512, 2) void ffn1_kernel(
    const bf16_t* __restrict__ xn, const bf16_t* __restrict__ w1t,
    const float* __restrict__ b1, const int* __restrict__ tok,
    const int* __restrict__ cnt, const int* __restrict__ offs,
    bf16_t* __restrict__ h1)
{
    const int e = blockIdx.z;
    const int c = cnt[e];
    const int m0 = blockIdx.y * 256;
    if (m0 >= c) return;
    const int n0 = blockIdx.x * 256;
    const int off = offs[e];

    __shared__ __align__(16) bf16_t S[2 * 4 * 8192];   // 128 KiB

    const int tid = threadIdx.x;
    const int rloc = tid >> 3;
    const int qx8 = ((tid & 7) ^ (rloc & 7)) * 8;

    int mA0 = m0 + rloc;        if (mA0 >= c) mA0 = c - 1;
    int mA1 = m0 + 64 + rloc;   if (mA1 >= c) mA1 = c - 1;
    int mA2 = m0 + 128 + rloc;  if (mA2 >= c) mA2 = c - 1;
    int mA3 = m0 + 192 + rloc;  if (mA3 >= c) mA3 = c - 1;
    const bf16_t* pa0 = xn + (size_t)tok[off + mA0] * DD + qx8;
    const bf16_t* pa1 = xn + (size_t)tok[off + mA1] * DD + qx8;
    const bf16_t* pa2 = xn + (size_t)tok[off + mA2] * DD + qx8;
    const bf16_t* pa3 = xn + (size_t)tok[off + mA3] * DD + qx8;
    const bf16_t* pb0 = w1t + ((size_t)e * HH + n0 + rloc) * DD + qx8;
    const bf16_t* pb1 = pb0 + (size_t)64 * DD;
    const bf16_t* pb2 = pb0 + (size_t)128 * DD;
    const bf16_t* pb3 = pb0 + (size_t)192 * DD;

    f32x4 acc[8][4] = {};
    mfma_mainloop<DD / 64>(pa0, pa1, pa2, pa3, pb0, pb1, pb2, pb3, S, acc);

    const int lane = tid & 63, wave = tid >> 6;
    const int wm = wave >> 2, wn = wave & 3;
    const int l15 = lane & 15, lq = lane >> 4;

    const float* b1e = b1 + (size_t)e * HH;
#pragma unroll
    for (int tf = 0; tf < 8; ++tf) {
        int m = m0 + wm * 128 + tf * 16 + l15;
        if (m < c) {
            bf16_t* hrow = h1 + (size_t)(off + m) * HH;
#pragma unroll
            for (int nf = 0; nf < 4; ++nf) {
                int n = n0 + (nf >> 1) * 128 + wn * 32 + (nf & 1) * 16 + lq * 4;
                float4 bb = *(const float4*)(b1e + n);
                f32x4 a = acc[tf][nf];
                bf16x4 pk;
                pk[0] = (bf16_t)gelu_fast(a[0] + bb.x);
                pk[1] = (bf16_t)gelu_fast(a[1] + bb.y);
                pk[2] = (bf16_t)gelu_fast(a[2] + bb.z);
                pk[3] = (bf16_t)gelu_fast(a[3] + bb.w);
                *(bf16x4*)(hrow + n) = pk;
            }
        }
    }
}

// ---------------- FFN2: y = (h1 @ W2 + b2) * gate ----------------
__global__ __launch_bounds__(512, 2) void ffn2_kernel(
    const bf16_t* __restrict__ h1, const bf16_t* __restrict__ w2t,
    const float* __restrict__ b2, const float* __restrict__ gatev,
    const int* __restrict__ cnt, const int* __restrict__ offs,
    bf16_t* __restrict__ yv)
{
    const int e = blockIdx.z;
    const int c = cnt[e];
    const int m0 = blockIdx.y * 256;
    if (m0 >= c) return;
    const int n0 = blockIdx.x * 256;
    const int off = offs[e];

    __shared__ __align__(16) bf16_t S[2 * 4 * 8192];   // 128 KiB

    const int tid = threadIdx.x;
    const int rloc = tid >> 3;
    const int qx8 = ((tid & 7) ^ (rloc & 7)) * 8;

    int mA0 = m0 + rloc;        if (mA0 >= c) mA0 = c - 1;
    int mA1 = m0 + 64 + rloc;   if (mA1 >= c) mA1 = c - 1;
    int mA2 = m0 + 128 + rloc;  if (mA2 >= c) mA2 = c - 1;
    int mA3 = m0 + 192 + rloc;  if (mA3 >= c) mA3 = c - 1;
    const bf16_t* pa0 = h1 + (size_t)(off + mA0) * HH + qx8;
    const bf16_t* pa1 = h1 + (size_t)(off + mA1) * HH + qx8;
    const bf16_t* pa2 = h1 + (size_t)(off + mA2) * HH + qx8;
    const bf16_t* pa3 = h1 + (size_t)(off + mA3) * HH + qx8;
    const bf16_t* pb0 = w2t + ((size_t)e * DD + n0 + rloc) * HH + qx8;
    const bf16_t* pb1 = pb0 + (size_t)64 * HH;
    const bf16_t* pb2 = pb0 + (size_t)128 * HH;
    const bf16_t* pb3 = pb0 + (size_t)192 * HH;

    f32x4 acc[8][4] = {};
    mfma_mainloop<HH / 64>(pa0, pa1, pa2, pa3, pb0, pb1, pb2, pb3, S, acc);

    const int lane = tid & 63, wave = tid >> 6;
    const int wm = wave >> 2, wn = wave & 3;
    const int l15 = lane & 15, lq = lane >> 4;

    const float* b2e = b2 + (size_t)e * DD;
#pragma unroll
    for (int tf = 0; tf < 8; ++tf) {
        int m = m0 + wm * 128 + tf * 16 + l15;
        if (m < c) {
            float g = gatev[off + m];
            bf16_t* yrow = yv + (size_t)(off + m) * DD;
#pragma unroll
            for (int nf = 0; nf < 4; ++nf) {
                int n = n0 + (nf >> 1) * 128 + wn * 32 + (nf & 1) * 16 + lq * 4;
                float4 bb = *(const float4*)(b2e + n);
                f32x4 a = acc[tf][nf];
                bf16x4 pk;
                pk[0] = (bf16_t)((a[0] + bb.x) * g);
                pk[1] = (bf16_t)((a[1] + bb.y) * g);
                pk[2] = (bf16_t)((a[2] + bb.z) * g);
                pk[3] = (bf16_t)((a[3] + bb.w) * g);
                *(bf16x4*)(yrow + n) = pk;
            }
        }
    }
}

// ---------------- combine: out = x + y[a0] + y[a1] ----------------
__global__ __launch_bounds__(256) void combine_kernel(
    const float* __restrict__ x, const bf16_t* __restrict__ yv,
    const int* __restrict__ a_of_t, float* __restrict__ outp)
{
    int t = blockIdx.x;
    int tid = threadIdx.x;
    int a0 = a_of_t[2*t], a1 = a_of_t[2*t+1];
    float4 xv = ((const float4*)(x + (size_t)t * DD))[tid];
    bf16x4 y0 = ((const bf16x4*)(yv + (size_t)a0 * DD))[tid];
    bf16x4 y1 = ((const bf16x4*)(yv + (size_t)a1 * DD))[tid];
    float4 o;
    o.x = xv.x + (float)y0[0] + (float)y1[0];
    o.y = xv.y + (float)y0[1] + (float)y1[1];
    o.z = xv.z + (float)y0[2] + (float)y1[2];
    o.w = xv.w + (float)y0[3] + (float)y1[3];
    ((float4*)(outp + (size_t)t * DD))[tid] = o;
}

extern "C" void kernel_launch(void* const* d_in, const int* in_sizes, int n_in,
                              void* d_out, int out_size, void* d_ws, size_t ws_size,
                              hipStream_t stream)
{
    const float* x      = (const float*)d_in[0];
    const float* gamma  = (const float*)d_in[1];
    const float* beta   = (const float*)d_in[2];
    const float* gate_w = (const float*)d_in[3];
    const float* W1     = (const float*)d_in[4];
    const float* b1     = (const float*)d_in[5];
    const float* W2     = (const float*)d_in[6];
    const float* b2     = (const float*)d_in[7];
    float* outp = (float*)d_out;
    float* bal_out = outp + (size_t)T_TOK * DD;

    char* ws = (char*)d_ws;
    size_t off = 0;
    auto alloc = [&](size_t bytes) {
        char* p = ws + off;
        off += (bytes + 255) & ~(size_t)255;
        return p;
    };
    bf16_t* xn   = (bf16_t*)alloc((size_t)T_TOK * DD * 2);
    bf16_t* w1t  = (bf16_t*)alloc((size_t)EE * HH * DD * 2);
    bf16_t* w2t  = (bf16_t*)alloc((size_t)EE * DD * HH * 2);
    bf16_t* h1   = (bf16_t*)alloc((size_t)NA * HH * 2);
    bf16_t* yv   = (bf16_t*)alloc((size_t)NA * DD * 2);
    int*   tok     = (int*)alloc(NA * 4);
    float* gatev   = (float*)alloc(NA * 4);
    int*   a_of_t  = (int*)alloc(NA * 4);
    int*   tokexp  = (int*)alloc(NA * 4);
    float* tokgate = (float*)alloc(NA * 4);
    int*   blockcnt  = (int*)alloc(NBLK * EE * 4);
    float* blockgsum = (float*)alloc(NBLK * EE * 4);
    int*   basep     = (int*)alloc(NBLK * EE * 4);
    int*   cnt  = (int*)alloc(EE * 4);
    int*   offs = (int*)alloc(EE * 4);

    convT_kernel<<<dim3(HH/64, DD/64, EE), 256, 0, stream>>>(W1, w1t, DD, HH);
    convT_kernel<<<dim3(DD/64, HH/64, EE), 256, 0, stream>>>(W2, w2t, HH, DD);
    ln_gate_kernel<<<T_TOK, 256, 0, stream>>>(x, gamma, beta, gate_w, xn, tokexp, tokgate);
    hist_kernel<<<NBLK, 256, 0, stream>>>(tokexp, tokgate, blockcnt, blockgsum);
    offs_bal_kernel<<<1, 64, 0, stream>>>(blockcnt, blockgsum, cnt, offs, basep, bal_out);
    scatter_kernel<<<NBLK, 256, 0, stream>>>(tokexp, tokgate, basep, tok, gatev, a_of_t);
    ffn1_kernel<<<dim3(HH/256, 32, EE), 512, 0, stream>>>(xn, w1t, b1, tok, cnt, offs, h1);
    ffn2_kernel<<<dim3(DD/256, 32, EE), 512, 0, stream>>>(h1, w2t, b2, gatev, cnt, offs, yv);
    combine_kernel<<<T_TOK, 256, 0, stream>>>(x, yv, a_of_t, outp);
}

// Round 4
// 754.449 us; speedup vs baseline: 1.1564x; 1.0362x over previous
//
#include <hip/hip_runtime.h>
#include <hip/hip_bf16.h>

#define T_TOK 8192
#define DD 1024
#define EE 8
#define HH 4096
#define NA (2 * T_TOK)          // 16384 assignments
#define NBLK (NA / 256)         // 64 histogram/scatter blocks

typedef __bf16 bf16_t;
typedef __bf16 bf16x8 __attribute__((ext_vector_type(8)));
typedef __bf16 bf16x4 __attribute__((ext_vector_type(4)));
typedef float f32x4 __attribute__((ext_vector_type(4)));
typedef int   i32x4 __attribute__((ext_vector_type(4)));

union frag_u { i32x4 i; bf16x8 b; };

#define GLDS(g, l) __builtin_amdgcn_global_load_lds( \
    (const __attribute__((address_space(1))) void*)(g), \
    (__attribute__((address_space(3))) void*)(l), 16, 0, 0)

// inline-asm ds_read_b128: invisible to the memory legalizer (no auto vmcnt(0))
#define DSR(d, a)      asm volatile("ds_read_b128 %0, %1"           : "=v"(d) : "v"(a))
#define DSRO(d, a, O)  asm volatile("ds_read_b128 %0, %1 offset:" O : "=v"(d) : "v"(a))

#define VMW(N)  asm volatile("s_waitcnt vmcnt(" #N ")" ::: "memory")
#define LGK(N)  do { asm volatile("s_waitcnt lgkmcnt(" #N ")" ::: "memory"); \
                     __builtin_amdgcn_sched_barrier(0); } while (0)

// tanh-form GELU: gelu(v) = v * t / (t + 1), t = exp2(2/ln2 * u),
// u = 0.7978845608*(v + 0.044715 v^3). Max dev vs erf-GELU ~5e-4.
__device__ __forceinline__ float gelu_fast(float v) {
    float u = v * (0.79788456080286536f + 0.035677408136300125f * v * v);
    float a = 2.8853900817779268f * u;
    a = fminf(fmaxf(a, -87.0f), 87.0f);
    float t = __builtin_amdgcn_exp2f(a);
    return v * t * __builtin_amdgcn_rcpf(t + 1.0f);
}

// ---------------- LayerNorm + gating ----------------
__global__ __launch_bounds__(256) void ln_gate_kernel(
    const float* __restrict__ x, const float* __restrict__ gamma,
    const float* __restrict__ beta, const float* __restrict__ gate_w,
    bf16_t* __restrict__ xn, int* __restrict__ tokexp, float* __restrict__ tokgate)
{
    const int t = blockIdx.x;
    const int tid = threadIdx.x;
    const int lane = tid & 63, wave = tid >> 6;
    __shared__ float wred[4];
    __shared__ float stats[2];
    __shared__ float lred[32];
    __shared__ float logitsS[8];

    float4 v = ((const float4*)(x + (size_t)t * DD))[tid];
    float s = v.x + v.y + v.z + v.w;
#pragma unroll
    for (int o = 32; o > 0; o >>= 1) s += __shfl_down(s, o, 64);
    if (lane == 0) wred[wave] = s;
    __syncthreads();
    if (tid == 0) stats[0] = (wred[0] + wred[1] + wred[2] + wred[3]) * (1.0f / DD);
    __syncthreads();
    const float mu = stats[0];
    float d0 = v.x - mu, d1 = v.y - mu, d2 = v.z - mu, d3 = v.w - mu;
    float q = d0*d0 + d1*d1 + d2*d2 + d3*d3;
#pragma unroll
    for (int o = 32; o > 0; o >>= 1) q += __shfl_down(q, o, 64);
    __syncthreads();
    if (lane == 0) wred[wave] = q;
    __syncthreads();
    if (tid == 0) stats[1] = rsqrtf((wred[0]+wred[1]+wred[2]+wred[3]) * (1.0f / DD) + 1e-5f);
    __syncthreads();
    const float rstd = stats[1];
    float4 g4 = ((const float4*)gamma)[tid];
    float4 b4 = ((const float4*)beta)[tid];
    float n0 = d0 * rstd * g4.x + b4.x;
    float n1 = d1 * rstd * g4.y + b4.y;
    float n2 = d2 * rstd * g4.z + b4.z;
    float n3 = d3 * rstd * g4.w + b4.w;
    bf16x4 pk = { (bf16_t)n0, (bf16_t)n1, (bf16_t)n2, (bf16_t)n3 };
    ((bf16x4*)(xn + (size_t)t * DD))[tid] = pk;

    float part[8];
#pragma unroll
    for (int e = 0; e < 8; ++e) {
        float4 gw = ((const float4*)(gate_w + (size_t)e * DD))[tid];
        part[e] = n0 * gw.x + n1 * gw.y + n2 * gw.z + n3 * gw.w;
    }
#pragma unroll
    for (int e = 0; e < 8; ++e) {
        float p = part[e];
#pragma unroll
        for (int o = 32; o > 0; o >>= 1) p += __shfl_down(p, o, 64);
        if (lane == 0) lred[wave * 8 + e] = p;
    }
    __syncthreads();
    if (tid < 8) logitsS[tid] = lred[tid] + lred[8 + tid] + lred[16 + tid] + lred[24 + tid];
    __syncthreads();
    if (tid == 0) {
        float best = -1e30f; int e0 = 0;
        for (int e = 0; e < 8; ++e) { float le = logitsS[e]; if (le > best) { best = le; e0 = e; } }
        float best2 = -1e30f; int e1 = (e0 == 0) ? 1 : 0;
        for (int e = 0; e < 8; ++e) if (e != e0) { float le = logitsS[e]; if (le > best2) { best2 = le; e1 = e; } }
        float z = expf(best2 - best);
        float g0 = 1.0f / (1.0f + z);
        float g1 = z * g0;
        tokexp[2*t] = e0; tokexp[2*t+1] = e1;
        tokgate[2*t] = g0; tokgate[2*t+1] = g1;
    }
}

// ---------------- per-block histogram ----------------
__global__ __launch_bounds__(256) void hist_kernel(
    const int* __restrict__ tokexp, const float* __restrict__ tokgate,
    int* __restrict__ blockcnt, float* __restrict__ blockgsum)
{
    __shared__ int hcnt[EE];
    __shared__ float hg[EE];
    const int b = blockIdx.x, tid = threadIdx.x;
    if (tid < EE) { hcnt[tid] = 0; hg[tid] = 0.f; }
    __syncthreads();
    int idx = b * 256 + tid;
    int e = tokexp[idx];
    atomicAdd(&hcnt[e], 1);
    atomicAdd(&hg[e], tokgate[idx]);
    __syncthreads();
    if (tid < EE) {
        blockcnt[b * EE + tid] = hcnt[tid];
        blockgsum[b * EE + tid] = hg[tid];
    }
}

// ---------------- offsets + per-block bases + balance loss ----------------
__global__ __launch_bounds__(64) void offs_bal_kernel(
    const int* __restrict__ blockcnt, const float* __restrict__ blockgsum,
    int* __restrict__ cnt, int* __restrict__ offs, int* __restrict__ basep,
    float* __restrict__ bal_out)
{
    __shared__ int cntS[EE];
    const int tid = threadIdx.x;
    if (tid < EE) {
        int run = 0;
        for (int b = 0; b < NBLK; ++b) {
            basep[b * EE + tid] = run;
            run += blockcnt[b * EE + tid];
        }
        cnt[tid] = run;
        cntS[tid] = run;
    }
    __syncthreads();
    __shared__ int offsS[EE];
    if (tid == 0) {
        int run = 0; 
        for (int e = 0; e < EE; ++e) { offsS[e] = run; offs[e] = run; run += cntS[e]; }
        float bal = 0.f;
        for (int e = 0; e < EE; ++e) {
            float g = 0.f;
            for (int b = 0; b < NBLK; ++b) g += blockgsum[b * EE + e];
            float l = g * (1.0f / T_TOK) - (1.0f / EE);
            bal += l * l;
        }
        bal_out[0] = bal * (1.0f / EE);
    }
    __syncthreads();
    if (tid < EE) {
        for (int b = 0; b < NBLK; ++b) basep[b * EE + tid] += offsS[tid];
    }
}

// ---------------- scatter to assignment-major lists ----------------
__global__ __launch_bounds__(256) void scatter_kernel(
    const int* __restrict__ tokexp, const float* __restrict__ tokgate,
    const int* __restrict__ basep,
    int* __restrict__ tok, float* __restrict__ gatev, int* __restrict__ a_of_t)
{
    __shared__ int hcnt[EE];
    const int b = blockIdx.x, tid = threadIdx.x;
    if (tid < EE) hcnt[tid] = 0;
    __syncthreads();
    int idx = b * 256 + tid;
    int e = tokexp[idx];
    int r = atomicAdd(&hcnt[e], 1);
    int a = basep[b * EE + e] + r;
    tok[a] = idx >> 1;
    gatev[a] = tokgate[idx];
    a_of_t[idx] = a;
}

// ---------------- fp32 [E][R][C] -> bf16 [E][C][R] transpose ----------------
__global__ __launch_bounds__(256) void convT_kernel(
    const float* __restrict__ in, bf16_t* __restrict__ out, int R, int C)
{
    __shared__ float tile[64][65];
    int e = blockIdx.z;
    int c0 = blockIdx.x * 64, r0 = blockIdx.y * 64;
    int tx = threadIdx.x & 63, ty = threadIdx.x >> 6;
    const float* src = in + ((size_t)e * R + r0) * C + c0;
#pragma unroll
    for (int i = 0; i < 16; ++i) {
        int r = ty + i * 4;
        tile[r][tx] = src[(size_t)r * C + tx];
    }
    __syncthreads();
    bf16_t* dst = out + ((size_t)e * C + c0) * R + r0;
#pragma unroll
    for (int i = 0; i < 16; ++i) {
        int cc = ty + i * 4;
        dst[(size_t)cc * R + tx] = (bf16_t)tile[tx][cc];
    }
}

// =====================================================================
// 256x256 tile, BK=64, 8 waves. ONE barrier per K-tile; counted lgkmcnt
// clusters overlap LDS reads with MFMA; GLDS for tile kt+1 issued at the
// top of tile kt's compute so the next vmcnt(0) is ~free.
// LDS per buffer (bf16 elems): A rows0-63 @0, rows64-127 @4096,
// B rows0-63 @8192, rows64-127 @12288, A rows128-191 @16384,
// rows192-255 @20480, B rows128-191 @24576, rows192-255 @28672.
// Wave (wm,wn): A rows wm*128+{0..127}; B cols {0,128}+wn*32+{0..31}.
// Reads per tile per wave: A0(8,k-paired) Blo(4) Bhi(4) ... A1(8,k-paired).
// Clusters: C1(mq0,nf0-1)@lgk4  C2(mq0,nf2-3)@lgk0
//           C3(tf4-5,all nf)@lgk4  C4(tf6-7,all nf)@lgk0
// =====================================================================

#define MMC(tf, nf) \
    acc[tf][nf] = __builtin_amdgcn_mfma_f32_16x16x32_bf16(bF[nf][0].b, aF[(tf)&3][0].b, acc[tf][nf], 0,0,0); \
    acc[tf][nf] = __builtin_amdgcn_mfma_f32_16x16x32_bf16(bF[nf][1].b, aF[(tf)&3][1].b, acc[tf][nf], 0,0,0);

#define LOAD_A_P(mq_) do { \
    uint32_t a0_ = abase0 + rb + (mq_)*8192u; \
    uint32_t a1_ = abase1 + rb + (mq_)*8192u; \
    DSR (aF[0][0].i, a0_);         DSR (aF[0][1].i, a1_); \
    DSRO(aF[1][0].i, a0_, "2048"); DSRO(aF[1][1].i, a1_, "2048"); \
    DSRO(aF[2][0].i, a0_, "4096"); DSRO(aF[2][1].i, a1_, "4096"); \
    DSRO(aF[3][0].i, a0_, "6144"); DSRO(aF[3][1].i, a1_, "6144"); \
} while (0)

#define LOAD_B_ALL() do { \
    uint32_t l0 = bbase0 + rb; \
    uint32_t l1 = bbase1 + rb; \
    DSR (bF[0][0].i, l0);           DSRO(bF[1][0].i, l0, "2048"); \
    DSR (bF[0][1].i, l1);           DSRO(bF[1][1].i, l1, "2048"); \
    DSRO(bF[2][0].i, l0, "32768");  DSRO(bF[3][0].i, l0, "34816"); \
    DSRO(bF[2][1].i, l1, "32768");  DSRO(bF[3][1].i, l1, "34816"); \
} while (0)

template<int NT>
__device__ __forceinline__ void mfma_mainloop(
    const bf16_t* pa0, const bf16_t* pa1, const bf16_t* pa2, const bf16_t* pa3,
    const bf16_t* pb0, const bf16_t* pb1, const bf16_t* pb2, const bf16_t* pb3,
    bf16_t* S, f32x4 (&acc)[8][4])
{
    const int tid = threadIdx.x;
    const int lane = tid & 63, wave = tid >> 6;
    const int wm = wave >> 2, wn = wave & 3;
    const int l15 = lane & 15, lq = lane >> 4, rx = l15 & 7;
    const uint32_t csb0 = (uint32_t)((lq ^ rx) * 16);
    const uint32_t csb1 = (uint32_t)(((4 + lq) ^ rx) * 16);
    const uint32_t sbase = (uint32_t)(size_t)(__attribute__((address_space(3))) bf16_t*)S;
    const uint32_t abase0 = sbase + (uint32_t)wm*32768u + (uint32_t)l15*128u + csb0;
    const uint32_t abase1 = sbase + (uint32_t)wm*32768u + (uint32_t)l15*128u + csb1;
    const uint32_t bbase0 = sbase + 16384u + (uint32_t)wn*4096u + (uint32_t)l15*128u + csb0;
    const uint32_t bbase1 = sbase + 16384u + (uint32_t)wn*4096u + (uint32_t)l15*128u + csb1;

    frag_u aF[4][2];
    frag_u bF[4][2];

    // prologue: stage tile 0 into buf0 (8 GLDS; vm waited at loop top)
    {
        bf16_t* wb = S;
        GLDS(pa0, wb +     0 + tid*8); pa0 += 64;   // A rows   0- 63
        GLDS(pa1, wb +  4096 + tid*8); pa1 += 64;   // A rows  64-127
        GLDS(pa2, wb + 16384 + tid*8); pa2 += 64;   // A rows 128-191
        GLDS(pa3, wb + 20480 + tid*8); pa3 += 64;   // A rows 192-255
        GLDS(pb0, wb +  8192 + tid*8); pb0 += 64;   // B rows   0- 63
        GLDS(pb1, wb + 12288 + tid*8); pb1 += 64;   // B rows  64-127
        GLDS(pb2, wb + 24576 + tid*8); pb2 += 64;   // B rows 128-191
        GLDS(pb3, wb + 28672 + tid*8); pb3 += 64;   // B rows 192-255
    }

    for (int kt = 0; kt < NT; ++kt) {
        const uint32_t rb = (uint32_t)(kt & 1) * 65536u;
        bf16_t* wb = S + (size_t)((kt + 1) & 1) * 32768;
        const bool more = (kt + 1 < NT);

        VMW(0);                          // own GLDS(kt) landed (issued ~1 tile ago)
        __builtin_amdgcn_s_barrier();    // all staging landed; all prev reads done

        LOAD_A_P(0);                     // 8 reads (A rows wm*128+0..63 zone)
        LOAD_B_ALL();                    // 8 reads (Blo 4 then Bhi 4)

        if (more) {                      // stage tile kt+1 early: latency hides
            GLDS(pa0, wb +     0 + tid*8); pa0 += 64;
            GLDS(pa1, wb +  4096 + tid*8); pa1 += 64;
            GLDS(pa2, wb + 16384 + tid*8); pa2 += 64;
            GLDS(pa3, wb + 20480 + tid*8); pa3 += 64;
            GLDS(pb0, wb +  8192 + tid*8); pb0 += 64;
            GLDS(pb1, wb + 12288 + tid*8); pb1 += 64;
            GLDS(pb2, wb + 24576 + tid*8); pb2 += 64;
            GLDS(pb3, wb + 28672 + tid*8); pb3 += 64;
        }

        LGK(4);                          // A0 + Blo ready (Bhi outstanding)
        __builtin_amdgcn_s_setprio(1);
        MMC(0,0) MMC(1,0) MMC(2,0) MMC(3,0)
        MMC(0,1) MMC(1,1) MMC(2,1) MMC(3,1)
        __builtin_amdgcn_s_setprio(0);

        LGK(0);                          // Bhi ready
        __builtin_amdgcn_s_setprio(1);
        MMC(0,2) MMC(1,2) MMC(2,2) MMC(3,2)
        MMC(0,3) MMC(1,3) MMC(2,3) MMC(3,3)
        __builtin_amdgcn_s_setprio(0);

        LOAD_A_P(1);                     // 8 reads, k-paired, reuse aF regs

        LGK(4);                          // aF[0],aF[1] (tf4,tf5) ready
        __builtin_amdgcn_s_setprio(1);
        MMC(4,0) MMC(4,1) MMC(4,2) MMC(4,3)
        MMC(5,0) MMC(5,1) MMC(5,2) MMC(5,3)
        __builtin_amdgcn_s_setprio(0);

        LGK(0);                          // aF[2],aF[3] (tf6,tf7) ready
        __builtin_amdgcn_s_setprio(1);
        MMC(6,0) MMC(6,1) MMC(6,2) MMC(6,3)
        MMC(7,0) MMC(7,1) MMC(7,2) MMC(7,3)
        __builtin_amdgcn_s_setprio(0);
    }
}

// ---------------- FFN1: h1 = gelu(xn[gathered] @ W1 + b1) ----------------
__global__ __launch_bounds__(512, 2) void ffn1_kernel(
    const bf16_t* __restrict__ xn, const bf16_t* __restrict__ w1t,
    const float* __restrict__ b1, const int* __restrict__ tok,
    const int* __restrict__ cnt, const int* __restrict__ offs,
    bf16_t* __restrict__ h1)
{
    const int e = blockIdx.z;
    const int c = cnt[e];
    const int m0 = blockIdx.y * 256;
    if (m0 >= c) return;
    const int n0 = blockIdx.x * 256;
    const int off = offs[e];

    __shared__ __align__(16) bf16_t S[2 * 4 * 8192];   // 128 KiB

    const int tid = threadIdx.x;
    const int rloc = tid >> 3;
    const int qx8 = ((tid & 7) ^ (rloc & 7)) * 8;

    int mA0 = m0 + rloc;        if (mA0 >= c) mA0 = c - 1;
    int mA1 = m0 + 64 + rloc;   if (mA1 >= c) mA1 = c - 1;
    int mA2 = m0 + 128 + rloc;  if (mA2 >= c) mA2 = c - 1;
    int mA3 = m0 + 192 + rloc;  if (mA3 >= c) mA3 = c - 1;
    const bf16_t* pa0 = xn + (size_t)tok[off + mA0] * DD + qx8;
    const bf16_t* pa1 = xn + (size_t)tok[off + mA1] * DD + qx8;
    const bf16_t* pa2 = xn + (size_t)tok[off + mA2] * DD + qx8;
    const bf16_t* pa3 = xn + (size_t)tok[off + mA3] * DD + qx8;
    const bf16_t* pb0 = w1t + ((size_t)e * HH + n0 + rloc) * DD + qx8;
    const bf16_t* pb1 = pb0 + (size_t)64 * DD;
    const bf16_t* pb2 = pb0 + (size_t)128 * DD;
    const bf16_t* pb3 = pb0 + (size_t)192 * DD;

    f32x4 acc[8][4] = {};
    mfma_mainloop<DD / 64>(pa0, pa1, pa2, pa3, pb0, pb1, pb2, pb3, S, acc);

    const int lane = tid & 63, wave = tid >> 6;
    const int wm = wave >> 2, wn = wave & 3;
    const int l15 = lane & 15, lq = lane >> 4;

    const float* b1e = b1 + (size_t)e * HH;
#pragma unroll
    for (int tf = 0; tf < 8; ++tf) {
        int m = m0 + wm * 128 + tf * 16 + l15;
        if (m < c) {
            bf16_t* hrow = h1 + (size_t)(off + m) * HH;
#pragma unroll
            for (int nf = 0; nf < 4; ++nf) {
                int n = n0 + (nf >> 1) * 128 + wn * 32 + (nf & 1) * 16 + lq * 4;
                float4 bb = *(const float4*)(b1e + n);
                f32x4 a = acc[tf][nf];
                bf16x4 pk;
                pk[0] = (bf16_t)gelu_fast(a[0] + bb.x);
                pk[1] = (bf16_t)gelu_fast(a[1] + bb.y);
                pk[2] = (bf16_t)gelu_fast(a[2] + bb.z);
                pk[3] = (bf16_t)gelu_fast(a[3] + bb.w);
                *(bf16x4*)(hrow + n) = pk;
            }
        }
    }
}

// ---------------- FFN2: y = (h1 @ W2 + b2) * gate ----------------
__global__ __launch_bounds__(512, 2) void ffn2_kernel(
    const bf16_t* __restrict__ h1, const bf16_t* __restrict__ w2t,
    const float* __restrict__ b2, const float* __restrict__ gatev,
    const int* __restrict__ cnt, const int* __restrict__ offs,
    bf16_t* __restrict__ yv)
{
    const int e = blockIdx.z;
    const int c = cnt[e];
    const int m0 = blockIdx.y * 256;
    if (m0 >= c) return;
    const int n0 = blockIdx.x * 256;
    const int off = offs[e];

    __shared__ __align__(16) bf16_t S[2 * 4 * 8192];   // 128 KiB

    const int tid = threadIdx.x;
    const int rloc = tid >> 3;
    const int qx8 = ((tid & 7) ^ (rloc & 7)) * 8;

    int mA0 = m0 + rloc;        if (mA0 >= c) mA0 = c - 1;
    int mA1 = m0 + 64 + rloc;   if (mA1 >= c) mA1 = c - 1;
    int mA2 = m0 + 128 + rloc;  if (mA2 >= c) mA2 = c - 1;
    int mA3 = m0 + 192 + rloc;  if (mA3 >= c) mA3 = c - 1;
    const bf16_t* pa0 = h1 + (size_t)(off + mA0) * HH + qx8;
    const bf16_t* pa1 = h1 + (size_t)(off + mA1) * HH + qx8;
    const bf16_t* pa2 = h1 + (size_t)(off + mA2) * HH + qx8;
    const bf16_t* pa3 = h1 + (size_t)(off + mA3) * HH + qx8;
    const bf16_t* pb0 = w2t + ((size_t)e * DD + n0 + rloc) * HH + qx8;
    const bf16_t* pb1 = pb0 + (size_t)64 * HH;
    const bf16_t* pb2 = pb0 + (size_t)128 * HH;
    const bf16_t* pb3 = pb0 + (size_t)192 * HH;

    f32x4 acc[8][4] = {};
    mfma_mainloop<HH / 64>(pa0, pa1, pa2, pa3, pb0, pb1, pb2, pb3, S, acc);

    const int lane = tid & 63, wave = tid >> 6;
    const int wm = wave >> 2, wn = wave & 3;
    const int l15 = lane & 15, lq = lane >> 4;

    const float* b2e = b2 + (size_t)e * DD;
#pragma unroll
    for (int tf = 0; tf < 8; ++tf) {
        int m = m0 + wm * 128 + tf * 16 + l15;
        if (m < c) {
            float g = gatev[off + m];
            bf16_t* yrow = yv + (size_t)(off + m) * DD;
#pragma unroll
            for (int nf = 0; nf < 4; ++nf) {
                int n = n0 + (nf >> 1) * 128 + wn * 32 + (nf & 1) * 16 + lq * 4;
                float4 bb = *(const float4*)(b2e + n);
                f32x4 a = acc[tf][nf];
                bf16x4 pk;
                pk[0] = (bf16_t)((a[0] + bb.x) * g);
                pk[1] = (bf16_t)((a[1] + bb.y) * g);
                pk[2] = (bf16_t)((a[2] + bb.z) * g);
                pk[3] = (bf16_t)((a[3] + bb.w) * g);
                *(bf16x4*)(yrow + n) = pk;
            }
        }
    }
}

// ---------------- combine: out = x + y[a0] + y[a1] ----------------
__global__ __launch_bounds__(256) void combine_kernel(
    const float* __restrict__ x, const bf16_t* __restrict__ yv,
    const int* __restrict__ a_of_t, float* __restrict__ outp)
{
    int t = blockIdx.x;
    int tid = threadIdx.x;
    int a0 = a_of_t[2*t], a1 = a_of_t[2*t+1];
    float4 xv = ((const float4*)(x + (size_t)t * DD))[tid];
    bf16x4 y0 = ((const bf16x4*)(yv + (size_t)a0 * DD))[tid];
    bf16x4 y1 = ((const bf16x4*)(yv + (size_t)a1 * DD))[tid];
    float4 o;
    o.x = xv.x + (float)y0[0] + (float)y1[0];
    o.y = xv.y + (float)y0[1] + (float)y1[1];
    o.z = xv.z + (float)y0[2] + (float)y1[2];
    o.w = xv.w + (float)y0[3] + (float)y1[3];
    ((float4*)(outp + (size_t)t * DD))[tid] = o;
}

extern "C" void kernel_launch(void* const* d_in, const int* in_sizes, int n_in,
                              void* d_out, int out_size, void* d_ws, size_t ws_size,
                              hipStream_t stream)
{
    const float* x      = (const float*)d_in[0];
    const float* gamma  = (const float*)d_in[1];
    const float* beta   = (const float*)d_in[2];
    const float* gate_w = (const float*)d_in[3];
    const float* W1     = (const float*)d_in[4];
    const float* b1     = (const float*)d_in[5];
    const float* W2     = (const float*)d_in[6];
    const float* b2     = (const float*)d_in[7];
    float* outp = (float*)d_out;
    float* bal_out = outp + (size_t)T_TOK * DD;

    char* ws = (char*)d_ws;
    size_t off = 0;
    auto alloc = [&](size_t bytes) {
        char* p = ws + off;
        off += (bytes + 255) & ~(size_t)255;
        return p;
    };
    bf16_t* xn   = (bf16_t*)alloc((size_t)T_TOK * DD * 2);
    bf16_t* w1t  = (bf16_t*)alloc((size_t)EE * HH * DD * 2);
    bf16_t* w2t  = (bf16_t*)alloc((size_t)EE * DD * HH * 2);
    bf16_t* h1   = (bf16_t*)alloc((size_t)NA * HH * 2);
    bf16_t* yv   = (bf16_t*)alloc((size_t)NA * DD * 2);
    int*   tok     = (int*)alloc(NA * 4);
    float* gatev   = (float*)alloc(NA * 4);
    int*   a_of_t  = (int*)alloc(NA * 4);
    int*   tokexp  = (int*)alloc(NA * 4);
    float* tokgate = (float*)alloc(NA * 4);
    int*   blockcnt  = (int*)alloc(NBLK * EE * 4);
    float* blockgsum = (float*)alloc(NBLK * EE * 4);
    int*   basep     = (int*)alloc(NBLK * EE * 4);
    int*   cnt  = (int*)alloc(EE * 4);
    int*   offs = (int*)alloc(EE * 4);

    convT_kernel<<<dim3(HH/64, DD/64, EE), 256, 0, stream>>>(W1, w1t, DD, HH);
    convT_kernel<<<dim3(DD/64, HH/64, EE), 256, 0, stream>>>(W2, w2t, HH, DD);
    ln_gate_kernel<<<T_TOK, 256, 0, stream>>>(x, gamma, beta, gate_w, xn, tokexp, tokgate);
    hist_kernel<<<NBLK, 256, 0, stream>>>(tokexp, tokgate, blockcnt, blockgsum);
    offs_bal_kernel<<<1, 64, 0, stream>>>(blockcnt, blockgsum, cnt, offs, basep, bal_out);
    scatter_kernel<<<NBLK, 256, 0, stream>>>(tokexp, tokgate, basep, tok, gatev, a_of_t);
    ffn1_kernel<<<dim3(HH/256, 32, EE), 512, 0, stream>>>(xn, w1t, b1, tok, cnt, offs, h1);
    ffn2_kernel<<<dim3(DD/256, 32, EE), 512, 0, stream>>>(h1, w2t, b2, gatev, cnt, offs, yv);
    combine_kernel<<<T_TOK, 256, 0, stream>>>(x, yv, a_of_t, outp);
}